// Round 4
// baseline (1005.669 us; speedup 1.0000x reference)
//
#include <hip/hip_runtime.h>

// ReLU-RNN B=8192, T=1024, I=7, H=100, O=1 — barrier-free MFMA recurrence,
// TWO independent batch-chains per wave (fills single-wave latency stalls).
//
// State lives in a PERMUTED index space so the MFMA D-layout of step t is
// exactly the B-fragment layout of step t+1 on the same lane (see R3):
//   D position (ti, q, r) -> B slot k' = 32kt+8q+jj, ti<4: kt=ti,jj=r;
//   ti>=4: kt=ti-4, jj=4+r. W' pre-permuted once into 112 VGPRs (shared by
//   both chains). Unused k' slots (kt=3, jj>=4) carry x_t and the bias 1.0.
// Per step: 2 x 28 MFMA (interleaved) + in-register relu/pack + 8 prefetched
// x dword loads. NO LDS, NO barrier, NO cross-lane movement.
//
// Grid: 256 blocks x 64 threads = 1 wave/CU, 32 batch rows per wave.

typedef _Float16 half8 __attribute__((ext_vector_type(8)));
typedef float f32x4 __attribute__((ext_vector_type(4)));
typedef unsigned u32x4 __attribute__((ext_vector_type(4)));

static __device__ __forceinline__ unsigned pkrtz(float a, float b) {
    return __builtin_bit_cast(unsigned, __builtin_amdgcn_cvt_pkrtz(a, b));
}

__global__ __launch_bounds__(64, 1)
void rnn_wave2(const float* __restrict__ x,
               const float* __restrict__ W_ih,
               const float* __restrict__ W_hh,
               const float* __restrict__ b_ih,
               const float* __restrict__ b_hh,
               const float* __restrict__ W_fc,
               const float* __restrict__ b_fc,
               float* __restrict__ out) {
    const int l  = threadIdx.x;
    const int lm = l & 15;           // batch row within tile
    const int q  = l >> 4;           // quad
    const bool q1   = (q == 1);
    const bool qlt2 = (q < 2);

    const u32x4 zz = {0u, 0u, 0u, 0u};
    const half8 hzero = __builtin_bit_cast(half8, zz);

    // ---- W' fragments (constant all steps; shared by both chains) ----
    half8 w[7][4];
#pragma unroll
    for (int ti = 0; ti < 7; ++ti) {
        const int np = 16 * ti + lm;
#pragma unroll
        for (int kt = 0; kt < 4; ++kt) {
            half8 hw;
#pragma unroll
            for (int jj = 0; jj < 8; ++jj) {
                float v = 0.f;
                if (np < 100) {
                    if (jj < 4) {
                        int p = 16 * kt + 4 * q + jj;
                        if (p < 100) v = W_hh[np * 100 + p];
                    } else if (kt < 3) {
                        int p = 16 * (kt + 4) + 4 * q + (jj - 4);
                        if (p < 100) v = W_hh[np * 100 + p];
                    } else {
                        if (q == 0)      v = W_ih[np * 7 + (jj - 4)];
                        else if (q == 1) v = (jj < 7) ? W_ih[np * 7 + jj]
                                             : (b_ih[np] + b_hh[np]);
                    }
                }
                hw[jj] = (_Float16)v;
            }
            w[ti][kt] = hw;
        }
    }

    // ---- two chains: rows blk*32+lm (A) and +16 (B) ----
    const float* xrA = x + (size_t)(blockIdx.x * 32 + lm) * 7168;
    const float* xrB = xrA + (size_t)16 * 7168;
    const int o0 = q1 ? 4 : 0, o1 = o0 + 1, o2 = o0 + 2, o3 = q1 ? 6 : 3;

    half8 hfA[4], hfB[4];
    // t=0 state: h=0, x_0/bias in kt=3 tail
#pragma unroll
    for (int c = 0; c < 2; ++c) {
        const float* xr = c ? xrB : xrA;
        half8* hf = c ? hfB : hfA;
        float v0 = xr[o0], v1 = xr[o1], v2 = xr[o2], v3 = xr[o3];
        hf[0] = hzero; hf[1] = hzero; hf[2] = hzero;
        unsigned xd0 = pkrtz(v0, v1);
        unsigned xd1 = pkrtz(v2, q1 ? 1.0f : v3);
        if (!qlt2) { xd0 = 0u; xd1 = 0u; }
        u32x4 h3 = {0u, 0u, xd0, xd1};
        hf[3] = __builtin_bit_cast(half8, h3);
    }

    // depth-4 x prefetch per chain: slot s&3 holds x_s
    float xvA[4][4], xvB[4][4];
#pragma unroll
    for (int s = 1; s <= 4; ++s) {
        const float* pA = xrA + s * 7;
        const float* pB = xrB + s * 7;
        xvA[s & 3][0] = pA[o0]; xvA[s & 3][1] = pA[o1];
        xvA[s & 3][2] = pA[o2]; xvA[s & 3][3] = pA[o3];
        xvB[s & 3][0] = pB[o0]; xvB[s & 3][1] = pB[o1];
        xvB[s & 3][2] = pB[o2]; xvB[s & 3][3] = pB[o3];
    }

    const f32x4 kZ = {0.f, 0.f, 0.f, 0.f};
    f32x4 accA[7], accB[7];

    for (int tb = 0; tb < 1024; tb += 4) {
#pragma unroll
        for (int u = 0; u < 4; ++u) {
            const int t = tb + u;

            // 56 MFMAs, chains interleaved so B fills A's stalls
#pragma unroll
            for (int kt = 0; kt < 4; ++kt) {
                const int order[7] = {0, 4, 1, 5, 2, 6, 3};
#pragma unroll
                for (int oi = 0; oi < 7; ++oi) {
                    const int ti = order[oi];
                    accA[ti] = __builtin_amdgcn_mfma_f32_16x16x32_f16(
                        w[ti][kt], hfA[kt], (kt == 0) ? kZ : accA[ti], 0, 0, 0);
                    accB[ti] = __builtin_amdgcn_mfma_f32_16x16x32_f16(
                        w[ti][kt], hfB[kt], (kt == 0) ? kZ : accB[ti], 0, 0, 0);
                }
            }

            // repack: D -> next B fragment. relu via packed f16 max (frags 0-2);
            // frag 3 mixes acc (relu in f32) with x/bias (no relu).
            const int s = (u + 1) & 3;
#pragma unroll
            for (int c = 0; c < 2; ++c) {
                f32x4*  acc = c ? accB : accA;
                half8*  hf  = c ? hfB  : hfA;
                float*  xs  = c ? xvB[s] : xvA[s];
#pragma unroll
                for (int kt = 0; kt < 3; ++kt) {
                    u32x4 d;
                    d.x = pkrtz(acc[kt][0],     acc[kt][1]);
                    d.y = pkrtz(acc[kt][2],     acc[kt][3]);
                    d.z = pkrtz(acc[kt + 4][0], acc[kt + 4][1]);
                    d.w = pkrtz(acc[kt + 4][2], acc[kt + 4][3]);
                    half8 hv = __builtin_bit_cast(half8, d);
                    hf[kt] = __builtin_elementwise_max(hv, hzero);  // v_pk_max_f16
                }
                {
                    unsigned xd0 = pkrtz(xs[0], xs[1]);
                    unsigned xd1 = pkrtz(xs[2], q1 ? 1.0f : xs[3]);
                    if (!qlt2) { xd0 = 0u; xd1 = 0u; }
                    u32x4 d;
                    d.x = pkrtz(fmaxf(acc[3][0], 0.f), fmaxf(acc[3][1], 0.f));
                    d.y = pkrtz(fmaxf(acc[3][2], 0.f), fmaxf(acc[3][3], 0.f));
                    d.z = xd0; d.w = xd1;
                    hf[3] = __builtin_bit_cast(half8, d);
                }
            }

            // refill slot s with x_{t+5} for both chains
            int tn = t + 5; if (tn > 1023) tn = 1023;
            const float* pA = xrA + tn * 7;
            const float* pB = xrB + tn * 7;
            xvA[s][0] = pA[o0]; xvA[s][1] = pA[o1];
            xvA[s][2] = pA[o2]; xvA[s][3] = pA[o3];
            xvB[s][0] = pB[o0]; xvB[s][1] = pB[o1];
            xvB[s][2] = pB[o2]; xvB[s][3] = pB[o3];
        }
    }

    // ---- epilogue: acc holds pre-relu h_T (permuted space) for each chain ----
#pragma unroll
    for (int c = 0; c < 2; ++c) {
        f32x4* acc = c ? accB : accA;
        float sum = 0.f;
#pragma unroll
        for (int ti = 0; ti < 7; ++ti) {
#pragma unroll
            for (int r = 0; r < 4; ++r) {
                const int np = 16 * ti + 4 * q + r;
                const float wf = (np < 100) ? W_fc[np] : 0.f;
                sum += wf * fmaxf(acc[ti][r], 0.f);
            }
        }
        sum += __shfl_xor(sum, 16, 64);
        sum += __shfl_xor(sum, 32, 64);
        if (q == 0) out[blockIdx.x * 32 + c * 16 + lm] = sum + b_fc[0];
    }
}

extern "C" void kernel_launch(void* const* d_in, const int* in_sizes, int n_in,
                              void* d_out, int out_size, void* d_ws, size_t ws_size,
                              hipStream_t stream) {
    const float* x    = (const float*)d_in[0];
    const float* W_ih = (const float*)d_in[1];
    const float* W_hh = (const float*)d_in[2];
    const float* b_ih = (const float*)d_in[3];
    const float* b_hh = (const float*)d_in[4];
    const float* W_fc = (const float*)d_in[5];
    const float* b_fc = (const float*)d_in[6];
    float* out = (float*)d_out;

    rnn_wave2<<<dim3(256), dim3(64), 0, stream>>>(x, W_ih, W_hh, b_ih, b_hh, W_fc, b_fc, out);
}

// Round 5
// 658.191 us; speedup vs baseline: 1.5279x; 1.5279x over previous
//
#include <hip/hip_runtime.h>

// ReLU-RNN B=8192, T=1024, I=7, H=100, O=1 — barrier-free MFMA recurrence,
// software-pipelined step (R5). One chain (16 batch rows) per wave, 512 waves.
//
// Permuted state space (verified R3): D position (ti,q,r) holds state index
// p = 16ti+4q+r and feeds next step's B slot (kt,q,jj): jj<4 -> p=16kt+4q+jj,
// jj>=4,kt<3 -> p=16(kt+4)+4q+(jj-4); kt=3,jj>=4 carries x (q=0: x0..3,
// q=1: x4..6, bias). W' pre-permuted once into 112 VGPRs.
//
// Per-step floor = 28 MFMA x ~16 cyc/SIMD = 448 cyc. To approach it, the step
// is split so packs retire early and are consumed late:
//   Block A: acc{0,4,1,5} kt-interleaved (16 MFMAs) -> pack hfW[0] (hidden
//   under Block B); Block B: acc{2,6,3} (12 MFMAs) -> packs hfW[1..3] trail
//   ~40 cyc, first consumed 64+ cyc into the next step's MFMA stream.
// hf double-buffered (hfA/hfB) so early packs don't clobber live operands.
// sched_group_barrier pins the MFMA/VALU interleave (R4 showed the default
// scheduler clusters per-phase and serializes).

typedef _Float16 half8 __attribute__((ext_vector_type(8)));
typedef float f32x4 __attribute__((ext_vector_type(4)));
typedef unsigned u32x4 __attribute__((ext_vector_type(4)));

#define MF(a, b, c) __builtin_amdgcn_mfma_f32_16x16x32_f16((a), (b), (c), 0, 0, 0)
#define SGB __builtin_amdgcn_sched_group_barrier

static __device__ __forceinline__ unsigned pkrtz(float a, float b) {
    return __builtin_bit_cast(unsigned, __builtin_amdgcn_cvt_pkrtz(a, b));
}

__global__ __launch_bounds__(64, 1)
void rnn_pipe(const float* __restrict__ x,
              const float* __restrict__ W_ih,
              const float* __restrict__ W_hh,
              const float* __restrict__ b_ih,
              const float* __restrict__ b_hh,
              const float* __restrict__ W_fc,
              const float* __restrict__ b_fc,
              float* __restrict__ out) {
    const int l  = threadIdx.x;
    const int lm = l & 15;
    const int q  = l >> 4;
    const bool q1 = (q == 1);
    const unsigned xmask = (q < 2) ? 0xffffffffu : 0u;

    const u32x4 zz = {0u, 0u, 0u, 0u};
    const half8 hzero = __builtin_bit_cast(half8, zz);

    // ---- W' fragments (constant; 112 VGPRs) ----
    half8 w[7][4];
#pragma unroll
    for (int ti = 0; ti < 7; ++ti) {
        const int np = 16 * ti + lm;
#pragma unroll
        for (int kt = 0; kt < 4; ++kt) {
            half8 hw;
#pragma unroll
            for (int jj = 0; jj < 8; ++jj) {
                float v = 0.f;
                if (np < 100) {
                    if (jj < 4) {
                        int p = 16 * kt + 4 * q + jj;
                        if (p < 100) v = W_hh[np * 100 + p];
                    } else if (kt < 3) {
                        int p = 16 * (kt + 4) + 4 * q + (jj - 4);
                        if (p < 100) v = W_hh[np * 100 + p];
                    } else {
                        if (q == 0)      v = W_ih[np * 7 + (jj - 4)];
                        else if (q == 1) v = (jj < 7) ? W_ih[np * 7 + jj]
                                             : (b_ih[np] + b_hh[np]);
                    }
                }
                hw[jj] = (_Float16)v;
            }
            w[ti][kt] = hw;
        }
    }

    // ---- x addressing ----
    const float* xr = x + (size_t)(blockIdx.x * 16 + lm) * 7168;
    const int o0 = q1 ? 4 : 0, o1 = o0 + 1, o2 = o0 + 2, o3 = q1 ? 6 : 3;

    // t=0 state: h=0, x_0/bias tail
    half8 hfA[4], hfB[4];
    {
        float v0 = xr[o0], v1 = xr[o1], v2 = xr[o2], v3 = xr[o3];
        hfA[0] = hzero; hfA[1] = hzero; hfA[2] = hzero;
        unsigned xd0 = pkrtz(v0, v1) & xmask;
        unsigned xd1 = pkrtz(v2, q1 ? 1.0f : v3) & xmask;
        u32x4 h3 = {0u, 0u, xd0, xd1};
        hfA[3] = __builtin_bit_cast(half8, h3);
    }

    // depth-4 x prefetch: slot s&3 holds x_s
    float xv[4][4];
#pragma unroll
    for (int s = 1; s <= 4; ++s) {
        const float* p = xr + s * 7;
        xv[s & 3][0] = p[o0]; xv[s & 3][1] = p[o1];
        xv[s & 3][2] = p[o2]; xv[s & 3][3] = p[o3];
    }
    // rolling refill pointers: at step t, pa[0..2]/pb[0] = x_{t+5} components
    const float* pa = xr + 35 + o0;
    const float* pb = xr + 35 + o3;

    const f32x4 kZ = {0.f, 0.f, 0.f, 0.f};
    f32x4 acc[7];

#define PACKH(HWd, A, Bb)                                                     \
    { u32x4 d;                                                                \
      d.x = pkrtz(A[0], A[1]);  d.y = pkrtz(A[2], A[3]);                      \
      d.z = pkrtz(Bb[0], Bb[1]); d.w = pkrtz(Bb[2], Bb[3]);                   \
      half8 hv = __builtin_bit_cast(half8, d);                                \
      HWd = __builtin_elementwise_max(hv, hzero); }

#define STEP(HR, HW, S, T)                                                    \
    { /* Block A: acc 0,4,1,5 kt-interleaved (16 MFMAs) */                    \
      acc[0] = MF(w[0][0], HR[0], kZ);     acc[4] = MF(w[4][0], HR[0], kZ);   \
      acc[1] = MF(w[1][0], HR[0], kZ);     acc[5] = MF(w[5][0], HR[0], kZ);   \
      acc[0] = MF(w[0][1], HR[1], acc[0]); acc[4] = MF(w[4][1], HR[1], acc[4]);\
      acc[1] = MF(w[1][1], HR[1], acc[1]); acc[5] = MF(w[5][1], HR[1], acc[5]);\
      acc[0] = MF(w[0][2], HR[2], acc[0]); acc[4] = MF(w[4][2], HR[2], acc[4]);\
      acc[1] = MF(w[1][2], HR[2], acc[1]); acc[5] = MF(w[5][2], HR[2], acc[5]);\
      acc[0] = MF(w[0][3], HR[3], acc[0]); acc[4] = MF(w[4][3], HR[3], acc[4]);\
      acc[1] = MF(w[1][3], HR[3], acc[1]); acc[5] = MF(w[5][3], HR[3], acc[5]);\
      PACKH(HW[0], acc[0], acc[4]);   /* early pack, hidden under Block B */  \
      /* Block B: acc 2,6,3 kt-interleaved (12 MFMAs) */                      \
      acc[2] = MF(w[2][0], HR[0], kZ);     acc[6] = MF(w[6][0], HR[0], kZ);   \
      acc[3] = MF(w[3][0], HR[0], kZ);                                        \
      acc[2] = MF(w[2][1], HR[1], acc[2]); acc[6] = MF(w[6][1], HR[1], acc[6]);\
      acc[3] = MF(w[3][1], HR[1], acc[3]);                                    \
      acc[2] = MF(w[2][2], HR[2], acc[2]); acc[6] = MF(w[6][2], HR[2], acc[6]);\
      acc[3] = MF(w[3][2], HR[2], acc[3]);                                    \
      acc[2] = MF(w[2][3], HR[3], acc[2]); acc[6] = MF(w[6][3], HR[3], acc[6]);\
      acc[3] = MF(w[3][3], HR[3], acc[3]);                                    \
      PACKH(HW[1], acc[1], acc[5]);                                           \
      PACKH(HW[2], acc[2], acc[6]);                                           \
      { unsigned xd0 = pkrtz(xv[S][0], xv[S][1]) & xmask;                     \
        unsigned xd1 = pkrtz(xv[S][2], q1 ? 1.0f : xv[S][3]) & xmask;         \
        u32x4 d;                                                              \
        d.x = pkrtz(fmaxf(acc[3][0], 0.f), fmaxf(acc[3][1], 0.f));            \
        d.y = pkrtz(fmaxf(acc[3][2], 0.f), fmaxf(acc[3][3], 0.f));            \
        d.z = xd0; d.w = xd1;                                                 \
        HW[3] = __builtin_bit_cast(half8, d); }                               \
      if ((T) < 1019) {  /* refill slot S with x_{T+5}; stop before x OOB */  \
        xv[S][0] = pa[0]; xv[S][1] = pa[1]; xv[S][2] = pa[2]; xv[S][3] = pb[0];\
        pa += 7; pb += 7;                                                     \
      }                                                                       \
      /* pin schedule: A(16 MFMA) | pack0 | B(12 MFMA, VALU woven) | tail */  \
      SGB(8, 16, 0); SGB(2, 8, 0);                                            \
      SGB(8, 3, 0);  SGB(2, 4, 0);                                            \
      SGB(8, 3, 0);  SGB(2, 4, 0);                                            \
      SGB(8, 3, 0);  SGB(2, 4, 0);                                            \
      SGB(8, 3, 0);  SGB(2, 4, 0);                                            \
      SGB(32, 4, 0); SGB(2, 24, 0);                                           \
    }

    for (int tb = 0; tb < 1024; tb += 4) {
        STEP(hfA, hfB, 1, tb + 0)
        STEP(hfB, hfA, 2, tb + 1)
        STEP(hfA, hfB, 3, tb + 2)
        STEP(hfB, hfA, 0, tb + 3)
    }

    // ---- epilogue: acc holds pre-relu h_T (permuted space, batch = lm) ----
    float sum = 0.f;
#pragma unroll
    for (int ti = 0; ti < 7; ++ti) {
#pragma unroll
        for (int r = 0; r < 4; ++r) {
            const int np = 16 * ti + 4 * q + r;
            const float wf = (np < 100) ? W_fc[np] : 0.f;
            sum += wf * fmaxf(acc[ti][r], 0.f);
        }
    }
    sum += __shfl_xor(sum, 16, 64);
    sum += __shfl_xor(sum, 32, 64);
    if (q == 0) out[blockIdx.x * 16 + lm] = sum + b_fc[0];
}

extern "C" void kernel_launch(void* const* d_in, const int* in_sizes, int n_in,
                              void* d_out, int out_size, void* d_ws, size_t ws_size,
                              hipStream_t stream) {
    const float* x    = (const float*)d_in[0];
    const float* W_ih = (const float*)d_in[1];
    const float* W_hh = (const float*)d_in[2];
    const float* b_ih = (const float*)d_in[3];
    const float* b_hh = (const float*)d_in[4];
    const float* W_fc = (const float*)d_in[5];
    const float* b_fc = (const float*)d_in[6];
    float* out = (float*)d_out;

    rnn_pipe<<<dim3(512), dim3(64), 0, stream>>>(x, W_ih, W_hh, b_ih, b_hh, W_fc, b_fc, out);
}